// Round 4
// baseline (916.776 us; speedup 1.0000x reference)
//
#include <hip/hip_runtime.h>
#include <hip/hip_bf16.h>

#define N_NODES 100000
#define N_EDGES 3200000
#define CH 32
#define NK 9
#define YSTRIDE (NK * CH)  // 288

#define BNODES 64                              // destination nodes per bucket
#define NBUCK ((N_NODES + BNODES - 1) / BNODES) // 1563
#define CURS_PAD 16                            // one cursor per 64B line
#define TN 32                                  // nodes per yprep block

typedef __hip_bfloat16 bf16;

// ---------------------------------------------------------------------------
// Bucket histogram: LDS-aggregated, 256 grid-stride blocks
// ---------------------------------------------------------------------------
__global__ __launch_bounds__(256) void bhist_kernel(const int* __restrict__ ei_col,
                                                    int* __restrict__ hist) {
    __shared__ int h[NBUCK];
    for (int j = threadIdx.x; j < NBUCK; j += 256) h[j] = 0;
    __syncthreads();
    int stride = gridDim.x * 256;
    for (int e = blockIdx.x * 256 + threadIdx.x; e < N_EDGES; e += stride)
        atomicAdd(&h[ei_col[e] >> 6], 1);
    __syncthreads();
    for (int j = threadIdx.x; j < NBUCK; j += 256)
        if (h[j]) atomicAdd(&hist[j], h[j]);
}

// ---------------------------------------------------------------------------
// Single-block exclusive scan over NBUCK (<=2048) entries; writes bstart,
// sentinel, and padded cursors.
// ---------------------------------------------------------------------------
__global__ __launch_bounds__(1024) void bscan_kernel(const int* __restrict__ hist,
                                                     int* __restrict__ bstart,
                                                     int* __restrict__ cursor) {
    __shared__ int s[1024];
    int t = threadIdx.x;
    int a = (2 * t < NBUCK) ? hist[2 * t] : 0;
    int b = (2 * t + 1 < NBUCK) ? hist[2 * t + 1] : 0;
    s[t] = a + b;
    __syncthreads();
    for (int off = 1; off < 1024; off <<= 1) {
        int u = (t >= off) ? s[t - off] : 0;
        __syncthreads();
        s[t] += u;
        __syncthreads();
    }
    int excl = s[t] - (a + b);
    if (2 * t < NBUCK) {
        bstart[2 * t] = excl;
        cursor[2 * t * CURS_PAD] = excl;
    }
    if (2 * t + 1 < NBUCK) {
        bstart[2 * t + 1] = excl + a;
        cursor[(2 * t + 1) * CURS_PAD] = excl + a;
    }
    if (t == 1023) bstart[NBUCK] = s[1023];  // == N_EDGES
}

// ---------------------------------------------------------------------------
// Place 8-byte records {row|ia|ib|local_col, wa1_u16|wb1_u16} into bucket slots
// ---------------------------------------------------------------------------
__global__ __launch_bounds__(256) void place_kernel(const float* __restrict__ pseudo,
                                                    const int* __restrict__ ei,
                                                    int* __restrict__ cursor,
                                                    uint2* __restrict__ edata) {
    int e = blockIdx.x * 256 + threadIdx.x;
    if (e >= N_EDGES) return;
    int col = ei[N_EDGES + e];
    int row = ei[e];
    float2 pp = ((const float2*)pseudo)[e];
    float pa = fminf(fmaxf(pp.x, 0.f), 1.f);
    float pb = fminf(fmaxf(pp.y, 0.f), 1.f);
    int ia = pa < 0.5f ? 0 : 1;
    int ib = pb < 0.5f ? 0 : 1;
    float wa1 = 2.f * (pa - 0.5f * (float)ia);
    float wb1 = 2.f * (pb - 0.5f * (float)ib);
    unsigned qa = (unsigned)(wa1 * 65535.f + 0.5f);
    unsigned qb = (unsigned)(wb1 * 65535.f + 0.5f);
    int pos = atomicAdd(&cursor[(col >> 6) * CURS_PAD], 1);
    uint2 d;
    d.x = (unsigned)row | ((unsigned)ia << 17) | ((unsigned)ib << 18)
        | ((unsigned)(col & 63) << 20);
    d.y = qa | (qb << 16);
    edata[pos] = d;
}

// ---------------------------------------------------------------------------
// y[n,k,o] = sum_i x[n,i] * w[k,i,o]  (bf16, 57.6 MB)
// ---------------------------------------------------------------------------
__global__ __launch_bounds__(256) void yprep_kernel(const float* __restrict__ x,
                                                    const float* __restrict__ w,
                                                    bf16* __restrict__ y) {
    __shared__ float ws[NK * CH * CH];  // 36 KB, [k][i][o]
    __shared__ float xs[TN * 36];
    int tid = threadIdx.x;

    const float4* w4 = (const float4*)w;
    float4* ws4 = (float4*)ws;
    for (int j = tid; j < NK * CH * CH / 4; j += 256) ws4[j] = w4[j];

    int n0 = blockIdx.x * TN;
    {
        int n = tid >> 3, i4 = tid & 7;
        float4 v = ((const float4*)(x + (size_t)(n0 + n) * CH))[i4];
        *(float4*)(xs + n * 36 + i4 * 4) = v;
    }
    __syncthreads();

    int o4 = tid & 7;
    int g = tid >> 3;
    float4 acc[NK];
#pragma unroll
    for (int k = 0; k < NK; ++k) acc[k] = make_float4(0.f, 0.f, 0.f, 0.f);

    const float4* wsv = (const float4*)ws;
#pragma unroll 4
    for (int i = 0; i < CH; ++i) {
        float xv = xs[g * 36 + i];
#pragma unroll
        for (int k = 0; k < NK; ++k) {
            float4 wv = wsv[k * 256 + i * 8 + o4];
            acc[k].x += xv * wv.x;
            acc[k].y += xv * wv.y;
            acc[k].z += xv * wv.z;
            acc[k].w += xv * wv.w;
        }
    }

    bf16* yb = y + (size_t)(n0 + g) * YSTRIDE + o4 * 4;
#pragma unroll
    for (int k = 0; k < NK; ++k) {
        union { bf16 h[4]; uint2 u; } pk;
        pk.h[0] = __float2bfloat16(acc[k].x);
        pk.h[1] = __float2bfloat16(acc[k].y);
        pk.h[2] = __float2bfloat16(acc[k].z);
        pk.h[3] = __float2bfloat16(acc[k].w);
        *(uint2*)(yb + k * CH) = pk.u;
    }
}

// ---------------------------------------------------------------------------
// Bucket gather: one block per bucket of 64 destination nodes.
// LDS f32 accumulator (bank = channel, conflict-free); deg in LDS;
// normalize + root linear fused into write-out. Zero global atomics.
// ---------------------------------------------------------------------------
__global__ __launch_bounds__(256) void gather_kernel(const float* __restrict__ x,
                                                     const int* __restrict__ bstart,
                                                     const uint2* __restrict__ edata,
                                                     const bf16* __restrict__ y,
                                                     const float* __restrict__ rw,
                                                     const float* __restrict__ rb,
                                                     float* __restrict__ out) {
    __shared__ float acc[BNODES * CH];  // 8 KB
    __shared__ int degs[BNODES];
    __shared__ float rws[CH * CH];      // transposed
    __shared__ float rbs[CH];
    __shared__ uint2 stage[256];
    int tid = threadIdx.x;

    for (int j = tid; j < BNODES * CH; j += 256) acc[j] = 0.f;
    if (tid < BNODES) degs[tid] = 0;
    for (int j = tid; j < CH * CH; j += 256) {
        int o = j >> 5, i = j & 31;
        rws[i * CH + o] = rw[j];
    }
    if (tid < CH) rbs[tid] = rb[tid];
    __syncthreads();

    int b = blockIdx.x;
    int e0 = bstart[b], e1 = bstart[b + 1];
    int o = tid & 31, sub = tid >> 5;

    for (int c = e0; c < e1; c += 256) {
        int nc = min(256, e1 - c);
        if (tid < nc) stage[tid] = edata[c + tid];
        __syncthreads();
#pragma unroll 4
        for (int it = 0; it < 32; ++it) {
            int j = it * 8 + sub;
            if (j < nc) {
                uint2 ed = stage[j];
                int row = ed.x & 0x1FFFF;
                int ia = (ed.x >> 17) & 1;
                int ib = (ed.x >> 18) & 1;
                int lc = (ed.x >> 20) & 63;
                float wa1 = (float)(ed.y & 0xFFFF) * (1.f / 65535.f);
                float wb1 = (float)(ed.y >> 16) * (1.f / 65535.f);
                float wa0 = 1.f - wa1;
                float wb0 = 1.f - wb1;
                const bf16* yr = y + (size_t)row * YSTRIDE + (ia * 3 + ib) * CH + o;
                float m = (wa0 * wb0) * __bfloat162float(yr[0])
                        + (wa0 * wb1) * __bfloat162float(yr[CH])
                        + (wa1 * wb0) * __bfloat162float(yr[3 * CH])
                        + (wa1 * wb1) * __bfloat162float(yr[4 * CH]);
                atomicAdd(&acc[lc * CH + o], m);  // LDS atomic, bank=o
                if (o == 0) atomicAdd(&degs[lc], 1);
            }
        }
        __syncthreads();  // protect stage reuse
    }

    int nbase = b * BNODES;
#pragma unroll
    for (int k = 0; k < (BNODES * CH) / 256; ++k) {  // 8
        int idx = k * 256 + tid;
        int lc = idx >> 5, oo = idx & 31;
        int n = nbase + lc;
        if (n < N_NODES) {
            float a = acc[idx] / fmaxf((float)degs[lc], 1.f);
            const float* xr = x + (size_t)n * CH;
            float s = rbs[oo];
#pragma unroll
            for (int i = 0; i < CH; ++i) s += xr[i] * rws[i * CH + oo];
            out[n * CH + oo] = a + s;
        }
    }
}

// ---------------------------------------------------------------------------
extern "C" void kernel_launch(void* const* d_in, const int* in_sizes, int n_in,
                              void* d_out, int out_size, void* d_ws, size_t ws_size,
                              hipStream_t stream) {
    const float* x      = (const float*)d_in[0];
    const float* pseudo = (const float*)d_in[1];
    const float* weight = (const float*)d_in[2];
    const float* root_w = (const float*)d_in[3];
    const float* root_b = (const float*)d_in[4];
    const int*   ei     = (const int*)d_in[5];
    float* out = (float*)d_out;

    // ws layout (~83.5 MB total; >=110 MB proven available)
    int* hist    = (int*)d_ws;                 // 2048 ints
    int* bstart  = hist + 2048;                // NBUCK+1 (<2048)
    int* cursor  = bstart + 2048;              // NBUCK*16 ints = 100 KB
    char* base   = (char*)(cursor + NBUCK * CURS_PAD);
    size_t off   = ((size_t)(base - (char*)d_ws) + 1023) & ~(size_t)1023;
    uint2* edata = (uint2*)((char*)d_ws + off);         // 25.6 MB
    bf16* y      = (bf16*)(edata + N_EDGES);            // 57.6 MB

    hipMemsetAsync(hist, 0, NBUCK * sizeof(int), stream);
    bhist_kernel<<<256, 256, 0, stream>>>(ei + N_EDGES, hist);
    bscan_kernel<<<1, 1024, 0, stream>>>(hist, bstart, cursor);
    place_kernel<<<(N_EDGES + 255) / 256, 256, 0, stream>>>(pseudo, ei, cursor, edata);
    yprep_kernel<<<(N_NODES + TN - 1) / TN, 256, 0, stream>>>(x, weight, y);
    gather_kernel<<<NBUCK, 256, 0, stream>>>(x, bstart, edata, y, root_w, root_b, out);
}

// Round 5
// 461.505 us; speedup vs baseline: 1.9865x; 1.9865x over previous
//
#include <hip/hip_runtime.h>
#include <hip/hip_bf16.h>

#define N_NODES 100000
#define N_EDGES 3200000
#define CH 32
#define NK 9
#define KTOT 320                                // 288 z + 32 x (root plane)
#define RS 328                                  // LDS row stride (bf16) for zgemm

#define BNODES 64                               // destination nodes per bucket
#define NBUCK ((N_NODES + BNODES - 1) / BNODES) // 1563
#define CURS_PAD 16
#define MAXB 4096                               // max edges per bucket (mean 2048, sigma 45)

typedef __hip_bfloat16 bf16;
typedef __attribute__((ext_vector_type(8))) short bf16x8;
typedef __attribute__((ext_vector_type(4))) float f32x4;

// ---------------------------------------------------------------------------
// Bucket histogram
// ---------------------------------------------------------------------------
__global__ __launch_bounds__(256) void bhist_kernel(const int* __restrict__ ei_col,
                                                    int* __restrict__ hist) {
    __shared__ int h[NBUCK];
    for (int j = threadIdx.x; j < NBUCK; j += 256) h[j] = 0;
    __syncthreads();
    int stride = gridDim.x * 256;
    for (int e = blockIdx.x * 256 + threadIdx.x; e < N_EDGES; e += stride)
        atomicAdd(&h[ei_col[e] >> 6], 1);
    __syncthreads();
    for (int j = threadIdx.x; j < NBUCK; j += 256)
        if (h[j]) atomicAdd(&hist[j], h[j]);
}

// ---------------------------------------------------------------------------
// Single-block exclusive scan over buckets; writes bstart + sentinel + cursors
// ---------------------------------------------------------------------------
__global__ __launch_bounds__(1024) void bscan_kernel(const int* __restrict__ hist,
                                                     int* __restrict__ bstart,
                                                     int* __restrict__ cursor) {
    __shared__ int s[1024];
    int t = threadIdx.x;
    int a = (2 * t < NBUCK) ? hist[2 * t] : 0;
    int b = (2 * t + 1 < NBUCK) ? hist[2 * t + 1] : 0;
    s[t] = a + b;
    __syncthreads();
    for (int off = 1; off < 1024; off <<= 1) {
        int u = (t >= off) ? s[t - off] : 0;
        __syncthreads();
        s[t] += u;
        __syncthreads();
    }
    int excl = s[t] - (a + b);
    if (2 * t < NBUCK) {
        bstart[2 * t] = excl;
        cursor[2 * t * CURS_PAD] = excl;
    }
    if (2 * t + 1 < NBUCK) {
        bstart[2 * t + 1] = excl + a;
        cursor[(2 * t + 1) * CURS_PAD] = excl + a;
    }
    if (t == 1023) bstart[NBUCK] = s[1023];
}

// ---------------------------------------------------------------------------
// Coarse place: 8B records {row|ia|ib|lc, qa|qb} into bucket regions
// ---------------------------------------------------------------------------
__global__ __launch_bounds__(256) void place_kernel(const float* __restrict__ pseudo,
                                                    const int* __restrict__ ei,
                                                    int* __restrict__ cursor,
                                                    uint2* __restrict__ edata) {
    int e = blockIdx.x * 256 + threadIdx.x;
    if (e >= N_EDGES) return;
    int col = ei[N_EDGES + e];
    int row = ei[e];
    float2 pp = ((const float2*)pseudo)[e];
    float pa = fminf(fmaxf(pp.x, 0.f), 1.f);
    float pb = fminf(fmaxf(pp.y, 0.f), 1.f);
    int ia = pa < 0.5f ? 0 : 1;
    int ib = pb < 0.5f ? 0 : 1;
    float wa1 = 2.f * (pa - 0.5f * (float)ia);
    float wb1 = 2.f * (pb - 0.5f * (float)ib);
    unsigned qa = (unsigned)(wa1 * 65535.f + 0.5f);
    unsigned qb = (unsigned)(wb1 * 65535.f + 0.5f);
    int pos = atomicAdd(&cursor[(col >> 6) * CURS_PAD], 1);
    uint2 d;
    d.x = (unsigned)row | ((unsigned)ia << 17) | ((unsigned)ib << 18)
        | ((unsigned)(col & 63) << 20);
    d.y = qa | (qb << 16);
    edata[pos] = d;
}

// ---------------------------------------------------------------------------
// Per-bucket counting sort (in LDS) -> node-contiguous edata + nstart/ncnt.
// Reads sequential, writes land in a hot 32KB window (L2-resident, full lines).
// ---------------------------------------------------------------------------
__global__ __launch_bounds__(256) void bsort_kernel(const int* __restrict__ bstart,
                                                    uint2* __restrict__ edata,
                                                    int* __restrict__ nstart,
                                                    int* __restrict__ ncnt) {
    __shared__ uint2 buf[MAXB];   // 32 KB
    __shared__ int h[BNODES], off[BNODES], cur[BNODES];
    int tid = threadIdx.x;
    int b = blockIdx.x;
    int e0 = bstart[b], e1 = bstart[b + 1];
    int sz = e1 - e0;

    if (tid < BNODES) h[tid] = 0;
    for (int j = tid; j < sz; j += 256) buf[j] = edata[e0 + j];
    __syncthreads();
    for (int j = tid; j < sz; j += 256)
        atomicAdd(&h[(buf[j].x >> 20) & 63], 1);
    __syncthreads();
    if (tid == 0) {
        int s = 0;
        for (int l = 0; l < BNODES; ++l) { off[l] = s; s += h[l]; }
    }
    __syncthreads();
    if (tid < BNODES) {
        int n = b * BNODES + tid;
        if (n < N_NODES) { nstart[n] = e0 + off[tid]; ncnt[n] = h[tid]; }
        cur[tid] = off[tid];
    }
    __syncthreads();
    for (int j = tid; j < sz; j += 256) {
        uint2 r = buf[j];
        int p = atomicAdd(&cur[(r.x >> 20) & 63], 1);
        edata[e0 + p] = r;
    }
}

// ---------------------------------------------------------------------------
// Per-node pull: one wave per node; halves alternate edges. Accumulates
// z[k][i] = sum_e c_k(e) * x[row_e][i] in registers, divides by deg, writes
// za[n] = [z(288) | x(32)] bf16. Zero LDS, zero atomics -> max occupancy.
// ---------------------------------------------------------------------------
__global__ __launch_bounds__(256) void gather_kernel(const float* __restrict__ x,
                                                     const int* __restrict__ nstart,
                                                     const int* __restrict__ ncnt,
                                                     const uint2* __restrict__ edata,
                                                     bf16* __restrict__ za) {
    int tid = threadIdx.x;
    int wid = tid >> 6;
    int lane = tid & 63;
    int half = lane >> 5;
    int i = lane & 31;   // input channel
    int n = blockIdx.x * 4 + wid;
    if (n >= N_NODES) return;

    int s0 = nstart[n];
    int dg = ncnt[n];
    float a0 = 0.f, a1 = 0.f, a2 = 0.f, a3 = 0.f, a4 = 0.f,
          a5 = 0.f, a6 = 0.f, a7 = 0.f, a8 = 0.f;

    for (int j = half; j < dg; j += 2) {
        uint2 ed = edata[s0 + j];          // uniform per half-wave
        int row = ed.x & 0x1FFFF;
        int ia = (ed.x >> 17) & 1;
        int ib = (ed.x >> 18) & 1;
        float wa1 = (float)(ed.y & 0xFFFF) * (1.f / 65535.f);
        float wb1 = (float)(ed.y >> 16) * (1.f / 65535.f);
        float wa0 = 1.f - wa1;
        float wb0 = 1.f - wb1;
        float xv = x[(size_t)row * CH + i];  // 128B coalesced per half-wave

        // branchless plane coefficients (grid index a in {0,1,2})
        float wA0 = ia ? 0.f : wa0;
        float wA1 = ia ? wa0 : wa1;
        float wA2 = ia ? wa1 : 0.f;
        float wB0 = ib ? 0.f : wb0;
        float wB1 = ib ? wb0 : wb1;
        float wB2 = ib ? wb1 : 0.f;
        float t0 = wA0 * xv, t1 = wA1 * xv, t2 = wA2 * xv;
        a0 += t0 * wB0; a1 += t0 * wB1; a2 += t0 * wB2;
        a3 += t1 * wB0; a4 += t1 * wB1; a5 += t1 * wB2;
        a6 += t2 * wB0; a7 += t2 * wB1; a8 += t2 * wB2;
    }

    a0 += __shfl_down(a0, 32); a1 += __shfl_down(a1, 32); a2 += __shfl_down(a2, 32);
    a3 += __shfl_down(a3, 32); a4 += __shfl_down(a4, 32); a5 += __shfl_down(a5, 32);
    a6 += __shfl_down(a6, 32); a7 += __shfl_down(a7, 32); a8 += __shfl_down(a8, 32);

    if (half == 0) {
        float inv = 1.f / fmaxf((float)dg, 1.f);
        bf16* zr = za + (size_t)n * KTOT + i;
        zr[0 * CH] = __float2bfloat16(a0 * inv);
        zr[1 * CH] = __float2bfloat16(a1 * inv);
        zr[2 * CH] = __float2bfloat16(a2 * inv);
        zr[3 * CH] = __float2bfloat16(a3 * inv);
        zr[4 * CH] = __float2bfloat16(a4 * inv);
        zr[5 * CH] = __float2bfloat16(a5 * inv);
        zr[6 * CH] = __float2bfloat16(a6 * inv);
        zr[7 * CH] = __float2bfloat16(a7 * inv);
        zr[8 * CH] = __float2bfloat16(a8 * inv);
        zr[9 * CH] = __float2bfloat16(x[(size_t)n * CH + i]);  // root plane
    }
}

// ---------------------------------------------------------------------------
// out = za @ [Wflat; root_w^T] + b   -- MFMA GEMM, M=100K, N=32, K=320
// A-frag: lane(row=l&15, k=8*(l>>4)+j); B-frag: lane(col=l&15, k=8*(l>>4)+j);
// C/D: col=l&15, row=(l>>4)*4+reg  (m89-verified layout)
// ---------------------------------------------------------------------------
__global__ __launch_bounds__(256) void zgemm_kernel(const bf16* __restrict__ za,
                                                    const float* __restrict__ w,
                                                    const float* __restrict__ rw,
                                                    const float* __restrict__ rb,
                                                    float* __restrict__ out) {
    __shared__ bf16 alds[64 * RS];   // 41.0 KB
    __shared__ bf16 blds[32 * RS];   // 20.5 KB
    int tid = threadIdx.x;
    int n0 = blockIdx.x * 64;

    // stage B^T: blds[col][k]; k<288 -> w[k*32+col], k>=288 -> rw[col*32 + (k-288)]
    for (int idx = tid; idx < 288 * 32; idx += 256) {
        int kk = idx >> 5, o = idx & 31;
        blds[o * RS + kk] = __float2bfloat16(w[idx]);
    }
    for (int idx = tid; idx < 32 * 32; idx += 256) {
        int i = idx >> 5, o = idx & 31;
        blds[o * RS + 288 + i] = __float2bfloat16(rw[o * 32 + i]);
    }
    // stage A: 64 rows x 320 bf16, 16B chunks, padded stride RS
    for (int it = 0; it < 10; ++it) {
        int j = it * 256 + tid;          // 2560 chunks
        int r = j / 40;
        int c = (j - r * 40) * 8;
        int n = n0 + r;
        uint4 v = make_uint4(0, 0, 0, 0);
        if (n < N_NODES) v = *(const uint4*)(za + (size_t)n * KTOT + c);
        *(uint4*)(alds + r * RS + c) = v;
    }
    __syncthreads();

    int l = tid & 63, wt = tid >> 6;
    int lr = l & 15, lq = l >> 4;
    f32x4 acc0 = {0.f, 0.f, 0.f, 0.f};
    f32x4 acc1 = {0.f, 0.f, 0.f, 0.f};
#pragma unroll
    for (int ks = 0; ks < 10; ++ks) {
        int kk = ks * 32 + lq * 8;
        bf16x8 a  = *(const bf16x8*)(alds + (wt * 16 + lr) * RS + kk);
        bf16x8 b0 = *(const bf16x8*)(blds + lr * RS + kk);
        bf16x8 b1 = *(const bf16x8*)(blds + (lr + 16) * RS + kk);
        acc0 = __builtin_amdgcn_mfma_f32_16x16x32_bf16(a, b0, acc0, 0, 0, 0);
        acc1 = __builtin_amdgcn_mfma_f32_16x16x32_bf16(a, b1, acc1, 0, 0, 0);
    }

    float bias0 = rb[lr], bias1 = rb[lr + 16];
    int rbase = n0 + wt * 16 + lq * 4;
#pragma unroll
    for (int r = 0; r < 4; ++r) {
        int n = rbase + r;
        if (n < N_NODES) {
            out[(size_t)n * CH + lr]      = acc0[r] + bias0;
            out[(size_t)n * CH + lr + 16] = acc1[r] + bias1;
        }
    }
}

// ---------------------------------------------------------------------------
extern "C" void kernel_launch(void* const* d_in, const int* in_sizes, int n_in,
                              void* d_out, int out_size, void* d_ws, size_t ws_size,
                              hipStream_t stream) {
    const float* x      = (const float*)d_in[0];
    const float* pseudo = (const float*)d_in[1];
    const float* weight = (const float*)d_in[2];
    const float* root_w = (const float*)d_in[3];
    const float* root_b = (const float*)d_in[4];
    const int*   ei     = (const int*)d_in[5];
    float* out = (float*)d_out;

    // ws layout (~86.3 MB; <=109.8 MB proven available)
    int* hist    = (int*)d_ws;                  // 2048
    int* bstart  = hist + 2048;                 // 2048 (NBUCK+1 used)
    int* cursor  = bstart + 2048;               // NBUCK*16 = 25008
    int* nstart  = cursor + 25008;              // 100032
    int* ncnt    = nstart + 100032;             // 100032
    char* basep  = (char*)(ncnt + 100032);
    size_t off   = ((size_t)(basep - (char*)d_ws) + 1023) & ~(size_t)1023;
    uint2* edata = (uint2*)((char*)d_ws + off);      // 25.6 MB
    bf16* za     = (bf16*)(edata + N_EDGES);         // 64.0 MB

    hipMemsetAsync(hist, 0, NBUCK * sizeof(int), stream);
    bhist_kernel<<<256, 256, 0, stream>>>(ei + N_EDGES, hist);
    bscan_kernel<<<1, 1024, 0, stream>>>(hist, bstart, cursor);
    place_kernel<<<(N_EDGES + 255) / 256, 256, 0, stream>>>(pseudo, ei, cursor, edata);
    bsort_kernel<<<NBUCK, 256, 0, stream>>>(bstart, edata, nstart, ncnt);
    gather_kernel<<<(N_NODES + 3) / 4, 256, 0, stream>>>(x, nstart, ncnt, edata, za);
    zgemm_kernel<<<(N_NODES + 63) / 64, 256, 0, stream>>>(za, weight, root_w, root_b, out);
}

// Round 6
// 297.992 us; speedup vs baseline: 3.0765x; 1.5487x over previous
//
#include <hip/hip_runtime.h>
#include <hip/hip_bf16.h>

#define N_NODES 100000
#define N_EDGES 3200000
#define CH 32
#define NK 9
#define KTOT 320                                // 288 z + 32 x (root plane)
#define RS 328                                  // LDS row stride (bf16) for zgemm

#define BNODES 256                              // destination nodes per bucket
#define NBUCK ((N_NODES + BNODES - 1) / BNODES) // 391
#define CURS_PAD 16
#define MAXB 9216                               // max edges/bucket (mean 8192, sd ~90)
#define CHE 8192                                // edges per place chunk
#define NCHUNK ((N_EDGES + CHE - 1) / CHE)      // 391

typedef __hip_bfloat16 bf16;
typedef __attribute__((ext_vector_type(8))) short bf16x8;
typedef __attribute__((ext_vector_type(4))) float f32x4;

// ---------------------------------------------------------------------------
// Bucket histogram (global)
// ---------------------------------------------------------------------------
__global__ __launch_bounds__(256) void bhist_kernel(const int* __restrict__ ei_col,
                                                    int* __restrict__ hist) {
    __shared__ int h[NBUCK];
    for (int j = threadIdx.x; j < NBUCK; j += 256) h[j] = 0;
    __syncthreads();
    int stride = gridDim.x * 256;
    for (int e = blockIdx.x * 256 + threadIdx.x; e < N_EDGES; e += stride)
        atomicAdd(&h[ei_col[e] >> 8], 1);
    __syncthreads();
    for (int j = threadIdx.x; j < NBUCK; j += 256)
        if (h[j]) atomicAdd(&hist[j], h[j]);
}

// ---------------------------------------------------------------------------
// Single-block exclusive scan over buckets; writes bstart + sentinel + cursors
// ---------------------------------------------------------------------------
__global__ __launch_bounds__(1024) void bscan_kernel(const int* __restrict__ hist,
                                                     int* __restrict__ bstart,
                                                     int* __restrict__ cursor) {
    __shared__ int s[1024];
    int t = threadIdx.x;
    int a = (2 * t < NBUCK) ? hist[2 * t] : 0;
    int b = (2 * t + 1 < NBUCK) ? hist[2 * t + 1] : 0;
    s[t] = a + b;
    __syncthreads();
    for (int off = 1; off < 1024; off <<= 1) {
        int u = (t >= off) ? s[t - off] : 0;
        __syncthreads();
        s[t] += u;
        __syncthreads();
    }
    int excl = s[t] - (a + b);
    if (2 * t < NBUCK) {
        bstart[2 * t] = excl;
        cursor[2 * t * CURS_PAD] = excl;
    }
    if (2 * t + 1 < NBUCK) {
        bstart[2 * t + 1] = excl + a;
        cursor[(2 * t + 1) * CURS_PAD] = excl + a;
    }
    if (t == 1023) bstart[NBUCK] = s[1023];
}

// ---------------------------------------------------------------------------
// Place with per-block batch allocation: each block histograms its 8192-edge
// chunk, reserves one contiguous run per bucket with a single global atomic,
// then scatters records into its private runs (single-XCD line ownership).
// Record: {row|ia|ib|lc(8b), qa|qb}
// ---------------------------------------------------------------------------
__global__ __launch_bounds__(256) void place_kernel(const float* __restrict__ pseudo,
                                                    const int* __restrict__ ei,
                                                    int* __restrict__ cursor,
                                                    uint2* __restrict__ edata) {
    __shared__ int h[NBUCK];
    __shared__ int gb[NBUCK];   // global write cursor per bucket (block-private run)
    int tid = threadIdx.x;
    int c0 = blockIdx.x * CHE;
    int cend = min(c0 + CHE, N_EDGES);

    for (int j = tid; j < NBUCK; j += 256) h[j] = 0;
    __syncthreads();
    for (int e = c0 + tid; e < cend; e += 256)
        atomicAdd(&h[ei[N_EDGES + e] >> 8], 1);
    __syncthreads();
    for (int j = tid; j < NBUCK; j += 256)
        gb[j] = h[j] ? atomicAdd(&cursor[j * CURS_PAD], h[j]) : 0;
    __syncthreads();

    for (int e = c0 + tid; e < cend; e += 256) {
        int col = ei[N_EDGES + e];
        int row = ei[e];
        float2 pp = ((const float2*)pseudo)[e];
        float pa = fminf(fmaxf(pp.x, 0.f), 1.f);
        float pb = fminf(fmaxf(pp.y, 0.f), 1.f);
        int ia = pa < 0.5f ? 0 : 1;
        int ib = pb < 0.5f ? 0 : 1;
        float wa1 = 2.f * (pa - 0.5f * (float)ia);
        float wb1 = 2.f * (pb - 0.5f * (float)ib);
        unsigned qa = (unsigned)(wa1 * 65535.f + 0.5f);
        unsigned qb = (unsigned)(wb1 * 65535.f + 0.5f);
        int pos = atomicAdd(&gb[col >> 8], 1);   // LDS atomic -> global slot
        uint2 d;
        d.x = (unsigned)row | ((unsigned)ia << 17) | ((unsigned)ib << 18)
            | ((unsigned)(col & 255) << 20);
        d.y = qa | (qb << 16);
        edata[pos] = d;
    }
}

// ---------------------------------------------------------------------------
// Per-bucket counting sort (in LDS) -> node-contiguous edata + nstart/ncnt
// ---------------------------------------------------------------------------
__global__ __launch_bounds__(256) void bsort_kernel(const int* __restrict__ bstart,
                                                    uint2* __restrict__ edata,
                                                    int* __restrict__ nstart,
                                                    int* __restrict__ ncnt) {
    __shared__ uint2 buf[MAXB];   // 72 KB
    __shared__ int h[BNODES], pfx[BNODES], cur[BNODES];
    int tid = threadIdx.x;
    int b = blockIdx.x;
    int e0 = bstart[b], e1 = bstart[b + 1];
    int sz = min(e1 - e0, MAXB);

    h[tid] = 0;
    for (int j = tid; j < sz; j += 256) buf[j] = edata[e0 + j];
    __syncthreads();
    for (int j = tid; j < sz; j += 256)
        atomicAdd(&h[(buf[j].x >> 20) & 255], 1);
    __syncthreads();
    // wave-parallel exclusive scan of h into pfx (Hillis-Steele, 256 wide)
    int v = h[tid];
    pfx[tid] = v;
    __syncthreads();
    for (int d = 1; d < 256; d <<= 1) {
        int u = (tid >= d) ? pfx[tid - d] : 0;
        __syncthreads();
        pfx[tid] += u;
        __syncthreads();
    }
    int exc = pfx[tid] - v;   // exclusive
    cur[tid] = exc;
    {
        int n = b * BNODES + tid;
        if (n < N_NODES) { nstart[n] = e0 + exc; ncnt[n] = v; }
    }
    __syncthreads();
    for (int j = tid; j < sz; j += 256) {
        uint2 r = buf[j];
        int p = atomicAdd(&cur[(r.x >> 20) & 255], 1);
        edata[e0 + p] = r;
    }
}

// ---------------------------------------------------------------------------
// Per-node pull: one wave per node; halves alternate edges. Accumulates
// z[k][i] in registers, divides by deg, writes za[n] = [z(288)|x(32)] bf16.
// ---------------------------------------------------------------------------
__global__ __launch_bounds__(256) void gather_kernel(const float* __restrict__ x,
                                                     const int* __restrict__ nstart,
                                                     const int* __restrict__ ncnt,
                                                     const uint2* __restrict__ edata,
                                                     bf16* __restrict__ za) {
    int tid = threadIdx.x;
    int wid = tid >> 6;
    int lane = tid & 63;
    int half = lane >> 5;
    int i = lane & 31;
    int n = blockIdx.x * 4 + wid;
    if (n >= N_NODES) return;

    int s0 = nstart[n];
    int dg = ncnt[n];
    float a0 = 0.f, a1 = 0.f, a2 = 0.f, a3 = 0.f, a4 = 0.f,
          a5 = 0.f, a6 = 0.f, a7 = 0.f, a8 = 0.f;

    for (int j = half; j < dg; j += 2) {
        uint2 ed = edata[s0 + j];
        int row = ed.x & 0x1FFFF;
        int ia = (ed.x >> 17) & 1;
        int ib = (ed.x >> 18) & 1;
        float wa1 = (float)(ed.y & 0xFFFF) * (1.f / 65535.f);
        float wb1 = (float)(ed.y >> 16) * (1.f / 65535.f);
        float wa0 = 1.f - wa1;
        float wb0 = 1.f - wb1;
        float xv = x[(size_t)row * CH + i];

        float wA0 = ia ? 0.f : wa0;
        float wA1 = ia ? wa0 : wa1;
        float wA2 = ia ? wa1 : 0.f;
        float wB0 = ib ? 0.f : wb0;
        float wB1 = ib ? wb0 : wb1;
        float wB2 = ib ? wb1 : 0.f;
        float t0 = wA0 * xv, t1 = wA1 * xv, t2 = wA2 * xv;
        a0 += t0 * wB0; a1 += t0 * wB1; a2 += t0 * wB2;
        a3 += t1 * wB0; a4 += t1 * wB1; a5 += t1 * wB2;
        a6 += t2 * wB0; a7 += t2 * wB1; a8 += t2 * wB2;
    }

    a0 += __shfl_down(a0, 32); a1 += __shfl_down(a1, 32); a2 += __shfl_down(a2, 32);
    a3 += __shfl_down(a3, 32); a4 += __shfl_down(a4, 32); a5 += __shfl_down(a5, 32);
    a6 += __shfl_down(a6, 32); a7 += __shfl_down(a7, 32); a8 += __shfl_down(a8, 32);

    if (half == 0) {
        float inv = 1.f / fmaxf((float)dg, 1.f);
        bf16* zr = za + (size_t)n * KTOT + i;
        zr[0 * CH] = __float2bfloat16(a0 * inv);
        zr[1 * CH] = __float2bfloat16(a1 * inv);
        zr[2 * CH] = __float2bfloat16(a2 * inv);
        zr[3 * CH] = __float2bfloat16(a3 * inv);
        zr[4 * CH] = __float2bfloat16(a4 * inv);
        zr[5 * CH] = __float2bfloat16(a5 * inv);
        zr[6 * CH] = __float2bfloat16(a6 * inv);
        zr[7 * CH] = __float2bfloat16(a7 * inv);
        zr[8 * CH] = __float2bfloat16(a8 * inv);
        zr[9 * CH] = __float2bfloat16(x[(size_t)n * CH + i]);
    }
}

// ---------------------------------------------------------------------------
// out = za @ [Wflat; root_w^T] + b  -- MFMA GEMM, M=100K, N=32, K=320
// ---------------------------------------------------------------------------
__global__ __launch_bounds__(256) void zgemm_kernel(const bf16* __restrict__ za,
                                                    const float* __restrict__ w,
                                                    const float* __restrict__ rw,
                                                    const float* __restrict__ rb,
                                                    float* __restrict__ out) {
    __shared__ bf16 alds[64 * RS];
    __shared__ bf16 blds[32 * RS];
    int tid = threadIdx.x;
    int n0 = blockIdx.x * 64;

    for (int idx = tid; idx < 288 * 32; idx += 256) {
        int kk = idx >> 5, o = idx & 31;
        blds[o * RS + kk] = __float2bfloat16(w[idx]);
    }
    for (int idx = tid; idx < 32 * 32; idx += 256) {
        int i = idx >> 5, o = idx & 31;
        blds[o * RS + 288 + i] = __float2bfloat16(rw[o * 32 + i]);
    }
    for (int it = 0; it < 10; ++it) {
        int j = it * 256 + tid;
        int r = j / 40;
        int c = (j - r * 40) * 8;
        int n = n0 + r;
        uint4 v = make_uint4(0, 0, 0, 0);
        if (n < N_NODES) v = *(const uint4*)(za + (size_t)n * KTOT + c);
        *(uint4*)(alds + r * RS + c) = v;
    }
    __syncthreads();

    int l = tid & 63, wt = tid >> 6;
    int lr = l & 15, lq = l >> 4;
    f32x4 acc0 = {0.f, 0.f, 0.f, 0.f};
    f32x4 acc1 = {0.f, 0.f, 0.f, 0.f};
#pragma unroll
    for (int ks = 0; ks < 10; ++ks) {
        int kk = ks * 32 + lq * 8;
        bf16x8 a  = *(const bf16x8*)(alds + (wt * 16 + lr) * RS + kk);
        bf16x8 b0 = *(const bf16x8*)(blds + lr * RS + kk);
        bf16x8 b1 = *(const bf16x8*)(blds + (lr + 16) * RS + kk);
        acc0 = __builtin_amdgcn_mfma_f32_16x16x32_bf16(a, b0, acc0, 0, 0, 0);
        acc1 = __builtin_amdgcn_mfma_f32_16x16x32_bf16(a, b1, acc1, 0, 0, 0);
    }

    float bias0 = rb[lr], bias1 = rb[lr + 16];
    int rbase = n0 + wt * 16 + lq * 4;
#pragma unroll
    for (int r = 0; r < 4; ++r) {
        int n = rbase + r;
        if (n < N_NODES) {
            out[(size_t)n * CH + lr]      = acc0[r] + bias0;
            out[(size_t)n * CH + lr + 16] = acc1[r] + bias1;
        }
    }
}

// ---------------------------------------------------------------------------
extern "C" void kernel_launch(void* const* d_in, const int* in_sizes, int n_in,
                              void* d_out, int out_size, void* d_ws, size_t ws_size,
                              hipStream_t stream) {
    const float* x      = (const float*)d_in[0];
    const float* pseudo = (const float*)d_in[1];
    const float* weight = (const float*)d_in[2];
    const float* root_w = (const float*)d_in[3];
    const float* root_b = (const float*)d_in[4];
    const int*   ei     = (const int*)d_in[5];
    float* out = (float*)d_out;

    int* hist    = (int*)d_ws;                  // 2048
    int* bstart  = hist + 2048;                 // 2048 (NBUCK+1 used)
    int* cursor  = bstart + 2048;               // NBUCK*16 = 6256
    int* nstart  = cursor + 8192;               // 100032
    int* ncnt    = nstart + 100032;             // 100032
    char* basep  = (char*)(ncnt + 100032);
    size_t off   = ((size_t)(basep - (char*)d_ws) + 1023) & ~(size_t)1023;
    uint2* edata = (uint2*)((char*)d_ws + off);      // 25.6 MB
    bf16* za     = (bf16*)(edata + N_EDGES);         // 64.0 MB

    hipMemsetAsync(hist, 0, NBUCK * sizeof(int), stream);
    bhist_kernel<<<256, 256, 0, stream>>>(ei + N_EDGES, hist);
    bscan_kernel<<<1, 1024, 0, stream>>>(hist, bstart, cursor);
    place_kernel<<<NCHUNK, 256, 0, stream>>>(pseudo, ei, cursor, edata);
    bsort_kernel<<<NBUCK, 256, 0, stream>>>(bstart, edata, nstart, ncnt);
    gather_kernel<<<(N_NODES + 3) / 4, 256, 0, stream>>>(x, nstart, ncnt, edata, za);
    zgemm_kernel<<<(N_NODES + 63) / 64, 256, 0, stream>>>(za, weight, root_w, root_b, out);
}